// Round 1
// baseline (116.326 us; speedup 1.0000x reference)
//
#include <hip/hip_runtime.h>
#include <math.h>

#define BATCH 4
#define NPTS 8192
#define TPB 256
#define RPT 4                       // rows per thread
#define ROWS_PER_BLOCK (TPB * RPT)  // 1024
#define ROW_TILES (NPTS / ROWS_PER_BLOCK)  // 8

// Kernel 1: partial row-mins of squared distance.
// grid = (ROW_TILES * S, BATCH, 2); block = TPB.
// For each row point x (from pred if dir==0 else label) and its column
// segment, compute  partial = x^2 + min_m (y^2_m - 2 x.y_m)  = min_m d2.
// Labels staged in LDS as float4(-2y0, -2y1, -2y2, y^2) -> inner loop is
// 3 FMA + min per pair, ds_read_b128 broadcast (conflict-free).
__global__ __launch_bounds__(TPB) void chamfer_partial(
    const float* __restrict__ pred, const float* __restrict__ label,
    float* __restrict__ ws, int S, int colsPerSeg) {
  const int tid = threadIdx.x;
  const int seg = blockIdx.x % S;
  const int rowTile = blockIdx.x / S;
  const int b = blockIdx.y;
  const int dir = blockIdx.z;
  const float* __restrict__ rows = (dir == 0) ? pred : label;
  const float* __restrict__ cols = (dir == 0) ? label : pred;

  float x0[RPT], x1[RPT], x2[RPT], x2n[RPT], mn[RPT];
  const int rowBase = rowTile * ROWS_PER_BLOCK;
#pragma unroll
  for (int r = 0; r < RPT; ++r) {
    const int row = rowBase + r * TPB + tid;
    const float* p = rows + ((size_t)b * NPTS + row) * 3;
    x0[r] = p[0];
    x1[r] = p[1];
    x2[r] = p[2];
    x2n[r] = x0[r] * x0[r] + x1[r] * x1[r] + x2[r] * x2[r];
    mn[r] = INFINITY;  // tracks min of (y^2 - 2 x.y)
  }

  __shared__ float4 sh[TPB];
  const int colBase = seg * colsPerSeg;
  for (int c0 = 0; c0 < colsPerSeg; c0 += TPB) {
    __syncthreads();
    {
      const int col = colBase + c0 + tid;
      const float* q = cols + ((size_t)b * NPTS + col) * 3;
      const float y0 = q[0], y1 = q[1], y2 = q[2];
      sh[tid] = make_float4(-2.0f * y0, -2.0f * y1, -2.0f * y2,
                            y0 * y0 + y1 * y1 + y2 * y2);
    }
    __syncthreads();
#pragma unroll 4
    for (int l = 0; l < TPB; l += 2) {
      const float4 ya = sh[l];
      const float4 yb = sh[l + 1];
#pragma unroll
      for (int r = 0; r < RPT; ++r) {
        float ta = fmaf(x0[r], ya.x, ya.w);
        ta = fmaf(x1[r], ya.y, ta);
        ta = fmaf(x2[r], ya.z, ta);
        float tb = fmaf(x0[r], yb.x, yb.w);
        tb = fmaf(x1[r], yb.y, tb);
        tb = fmaf(x2[r], yb.z, tb);
        mn[r] = fminf(mn[r], fminf(ta, tb));  // -> v_min3_f32 pattern
      }
    }
  }

#pragma unroll
  for (int r = 0; r < RPT; ++r) {
    const int row = rowBase + r * TPB + tid;
    ws[(((size_t)dir * BATCH + b) * S + seg) * NPTS + row] = x2n[r] + mn[r];
  }
}

// Kernel 2: per row, min over the S segment-partials, clamp, sqrt,
// scale by 1/(B*N), reduce, atomicAdd into scalar out.
// grid = 64 blocks x 256 threads, 4 rows/thread -> 65536 rows.
__global__ __launch_bounds__(256) void chamfer_reduce(
    const float* __restrict__ ws, float* __restrict__ out, int S) {
  const int g0 = blockIdx.x * 1024 + threadIdx.x;
  float sum = 0.0f;
#pragma unroll
  for (int k = 0; k < 4; ++k) {
    const int g = g0 + k * 256;
    const int db = g / NPTS;        // dir*BATCH + b, 0..7
    const int row = g & (NPTS - 1);
    const float* p = ws + (size_t)db * S * NPTS + row;
    float m = p[0];
    for (int s = 1; s < S; ++s) m = fminf(m, p[(size_t)s * NPTS]);
    m = fmaxf(m, 0.0f);
    sum += sqrtf(m);
  }
  sum *= (1.0f / (float)(BATCH * NPTS));
  for (int off = 32; off > 0; off >>= 1) sum += __shfl_down(sum, off, 64);
  __shared__ float ssum[4];
  const int wid = threadIdx.x >> 6;
  const int lane = threadIdx.x & 63;
  if (lane == 0) ssum[wid] = sum;
  __syncthreads();
  if (threadIdx.x == 0) atomicAdd(out, ssum[0] + ssum[1] + ssum[2] + ssum[3]);
}

extern "C" void kernel_launch(void* const* d_in, const int* in_sizes, int n_in,
                              void* d_out, int out_size, void* d_ws,
                              size_t ws_size, hipStream_t stream) {
  const float* pred = (const float*)d_in[0];
  const float* label = (const float*)d_in[1];
  float* out = (float*)d_out;
  float* ws = (float*)d_ws;

  // Choose segment count to fit workspace: need 2*BATCH*S*NPTS floats.
  int S = 16;
  while (S > 1 && (size_t)2 * BATCH * S * NPTS * sizeof(float) > ws_size)
    S >>= 1;
  const int colsPerSeg = NPTS / S;  // multiple of TPB for S <= 32

  hipMemsetAsync(d_out, 0, sizeof(float), stream);

  dim3 grid1(ROW_TILES * S, BATCH, 2);
  chamfer_partial<<<grid1, TPB, 0, stream>>>(pred, label, ws, S, colsPerSeg);
  chamfer_reduce<<<64, 256, 0, stream>>>(ws, out, S);
}

// Round 2
// 97.685 us; speedup vs baseline: 1.1908x; 1.1908x over previous
//
#include <hip/hip_runtime.h>
#include <math.h>

#define BATCH 4
#define NPTS 8192
#define TPB 256
#define RPT 4                              // rows per thread
#define ROWS_PER_BLOCK (TPB * RPT)         // 1024
#define ROW_TILES (NPTS / ROWS_PER_BLOCK)  // 8

// One row's min-update over two staged columns (ya, yb).
// 6 v_fma_f32 + 1 v_min3_f32 for 2 (row,col) pairs.
#define ROW2(mn, x0_, x1_, x2_)                                \
  do {                                                         \
    float ta = __builtin_fmaf((x0_), ya.x, ya.w);              \
    ta = __builtin_fmaf((x1_), ya.y, ta);                      \
    ta = __builtin_fmaf((x2_), ya.z, ta);                      \
    float tb = __builtin_fmaf((x0_), yb.x, yb.w);              \
    tb = __builtin_fmaf((x1_), yb.y, tb);                      \
    tb = __builtin_fmaf((x2_), yb.z, tb);                      \
    asm("v_min3_f32 %0, %0, %1, %2" : "+v"(mn) : "v"(ta), "v"(tb)); \
  } while (0)

// Kernel 1: partial row-mins of squared distance.
// grid = (ROW_TILES * S, BATCH, 2); block = TPB.
// partial[row] = x^2 + min_m (y^2_m - 2 x.y_m) over this column segment.
// Labels staged in LDS as float4(-2y0,-2y1,-2y2,y^2): inner loop is
// 3 FMA / pair + min3 / 2 pairs; ds_read_b128 broadcast, conflict-free.
// All per-row state in named scalars so it MUST stay in VGPRs (R1 run
// showed VGPR=24 -> compiler demoted the arrays and ~2.2x'd VALU work).
__global__ __launch_bounds__(TPB, 4) void chamfer_partial(
    const float* __restrict__ pred, const float* __restrict__ label,
    float* __restrict__ ws, float* __restrict__ out, int S, int colsPerSeg) {
  const int tid = threadIdx.x;
  const int seg = blockIdx.x % S;
  const int rowTile = blockIdx.x / S;
  const int b = blockIdx.y;
  const int dir = blockIdx.z;
  const float* __restrict__ rows = (dir == 0) ? pred : label;
  const float* __restrict__ cols = (dir == 0) ? label : pred;

  // Zero the output scalar once; stream order puts this before any
  // chamfer_reduce atomicAdd. Replaces a separate hipMemsetAsync dispatch.
  if (blockIdx.x == 0 && b == 0 && dir == 0 && tid == 0) out[0] = 0.0f;

  const int rowBase = rowTile * ROWS_PER_BLOCK;
  const float* p0 = rows + ((size_t)b * NPTS + rowBase + 0 * TPB + tid) * 3;
  const float* p1 = rows + ((size_t)b * NPTS + rowBase + 1 * TPB + tid) * 3;
  const float* p2 = rows + ((size_t)b * NPTS + rowBase + 2 * TPB + tid) * 3;
  const float* p3 = rows + ((size_t)b * NPTS + rowBase + 3 * TPB + tid) * 3;
  const float x00 = p0[0], x01 = p0[1], x02 = p0[2];
  const float x10 = p1[0], x11 = p1[1], x12 = p1[2];
  const float x20 = p2[0], x21 = p2[1], x22 = p2[2];
  const float x30 = p3[0], x31 = p3[1], x32 = p3[2];
  const float n0 = x00 * x00 + x01 * x01 + x02 * x02;
  const float n1 = x10 * x10 + x11 * x11 + x12 * x12;
  const float n2 = x20 * x20 + x21 * x21 + x22 * x22;
  const float n3 = x30 * x30 + x31 * x31 + x32 * x32;
  float mn0 = INFINITY, mn1 = INFINITY, mn2 = INFINITY, mn3 = INFINITY;

  __shared__ float4 sh[TPB];
  const int colBase = seg * colsPerSeg;
  for (int c0 = 0; c0 < colsPerSeg; c0 += TPB) {
    __syncthreads();
    {
      const int col = colBase + c0 + tid;
      const float* q = cols + ((size_t)b * NPTS + col) * 3;
      const float y0 = q[0], y1 = q[1], y2 = q[2];
      sh[tid] = make_float4(-2.0f * y0, -2.0f * y1, -2.0f * y2,
                            y0 * y0 + y1 * y1 + y2 * y2);
    }
    __syncthreads();
#pragma unroll 4
    for (int l = 0; l < TPB; l += 2) {
      const float4 ya = sh[l];
      const float4 yb = sh[l + 1];
      ROW2(mn0, x00, x01, x02);
      ROW2(mn1, x10, x11, x12);
      ROW2(mn2, x20, x21, x22);
      ROW2(mn3, x30, x31, x32);
    }
  }

  float* w = ws + (((size_t)dir * BATCH + b) * S + seg) * NPTS + rowBase + tid;
  w[0 * TPB] = n0 + mn0;
  w[1 * TPB] = n1 + mn1;
  w[2 * TPB] = n2 + mn2;
  w[3 * TPB] = n3 + mn3;
}

// Kernel 2: per row, min over the S segment-partials (fully unrolled ->
// independent coalesced loads), clamp, sqrt, scale, block-reduce,
// one atomicAdd per block. grid = 64 x 256, 4 rows/thread -> 65536 rows.
template <int S>
__global__ __launch_bounds__(256) void chamfer_reduce(
    const float* __restrict__ ws, float* __restrict__ out) {
  const int g0 = blockIdx.x * 1024 + threadIdx.x;
  float sum = 0.0f;
#pragma unroll
  for (int k = 0; k < 4; ++k) {
    const int g = g0 + k * 256;
    const int db = g >> 13;  // g / 8192 : dir*BATCH+b, 0..7
    const int row = g & (NPTS - 1);
    const float* p = ws + (size_t)db * S * NPTS + row;
    float m = INFINITY;
#pragma unroll
    for (int s = 0; s < S; ++s) m = fminf(m, p[(size_t)s * NPTS]);
    sum += sqrtf(fmaxf(m, 0.0f));
  }
  sum *= (1.0f / (float)(BATCH * NPTS));
  for (int off = 32; off > 0; off >>= 1) sum += __shfl_down(sum, off, 64);
  __shared__ float ssum[4];
  const int wid = threadIdx.x >> 6;
  const int lane = threadIdx.x & 63;
  if (lane == 0) ssum[wid] = sum;
  __syncthreads();
  if (threadIdx.x == 0) atomicAdd(out, ssum[0] + ssum[1] + ssum[2] + ssum[3]);
}

extern "C" void kernel_launch(void* const* d_in, const int* in_sizes, int n_in,
                              void* d_out, int out_size, void* d_ws,
                              size_t ws_size, hipStream_t stream) {
  const float* pred = (const float*)d_in[0];
  const float* label = (const float*)d_in[1];
  float* out = (float*)d_out;
  float* ws = (float*)d_ws;

  // Segment count chosen to fit workspace: need 2*BATCH*S*NPTS floats.
  // R1 confirmed ws_size >= 4 MB (S=16 ran, WRITE_SIZE 4 MB).
  int S = 16;
  while (S > 1 && (size_t)2 * BATCH * S * NPTS * sizeof(float) > ws_size)
    S >>= 1;
  const int colsPerSeg = NPTS / S;

  dim3 grid1(ROW_TILES * S, BATCH, 2);
  chamfer_partial<<<grid1, TPB, 0, stream>>>(pred, label, ws, out, S,
                                             colsPerSeg);
  switch (S) {
    case 16: chamfer_reduce<16><<<64, 256, 0, stream>>>(ws, out); break;
    case 8:  chamfer_reduce<8><<<64, 256, 0, stream>>>(ws, out); break;
    case 4:  chamfer_reduce<4><<<64, 256, 0, stream>>>(ws, out); break;
    case 2:  chamfer_reduce<2><<<64, 256, 0, stream>>>(ws, out); break;
    default: chamfer_reduce<1><<<64, 256, 0, stream>>>(ws, out); break;
  }
}